// Round 1
// baseline (2204.010 us; speedup 1.0000x reference)
//
#include <hip/hip_runtime.h>
#include <hip/hip_bf16.h>

#define HN 128        // rnn_size
#define TT 2048       // time steps
#define BATCH 64
#define G3 384        // 3*H
#define NTHREADS 768  // 2 k-halves * 384 columns

__device__ __forceinline__ float fast_sigmoid(float x) {
  // 1/(1+exp(-x)) via 1-ulp v_exp_f32 / v_rcp_f32 (error ~1e-7, fine vs 6.4e-5 thr)
  float e = __builtin_amdgcn_exp2f(-x * 1.44269504088896340736f);
  return __builtin_amdgcn_rcpf(1.0f + e);
}
__device__ __forceinline__ float fast_tanh(float x) {
  // tanh(x) = 1 - 2/(exp(2x)+1); saturates correctly for |x| large
  float e = __builtin_amdgcn_exp2f(x * 2.88539008177792681472f);
  return 1.0f - 2.0f * __builtin_amdgcn_rcpf(e + 1.0f);
}

__global__ __launch_bounds__(NTHREADS, 3) void gru_scan_kernel(
    const float* __restrict__ y, const float* __restrict__ u,
    const float* __restrict__ Wi_f, const float* __restrict__ bi_f,
    const float* __restrict__ Wh_f, const float* __restrict__ bhn_f,
    const float* __restrict__ Wi_b, const float* __restrict__ bi_b,
    const float* __restrict__ Wh_b, const float* __restrict__ bhn_b,
    float* __restrict__ feat)
{
  const int b   = blockIdx.x >> 1;
  const int dir = blockIdx.x & 1;
  const float* __restrict__ Wi  = dir ? Wi_b  : Wi_f;
  const float* __restrict__ bi  = dir ? bi_b  : bi_f;
  const float* __restrict__ Wh  = dir ? Wh_b  : Wh_f;
  const float* __restrict__ bhn = dir ? bhn_b : bhn_f;

  const int tid = threadIdx.x;
  const int c   = tid / 384;       // k-half: 0 -> k 0..63, 1 -> k 64..127
  const int j   = tid - c * 384;   // output column of h @ Wh
  const int k0  = c * 64;

  __shared__ float4 y_lds[TT];         // 32 KB: whole y row for this batch
  __shared__ float4 u_lds[TT];         // 32 KB
  __shared__ float  h_lds[HN];
  __shared__ float  hp_part[2][G3];

  // ---- one-time: stage y/u rows into LDS (coalesced float4) ----
  const float4* yg = reinterpret_cast<const float4*>(y) + (size_t)b * TT;
  const float4* ug = reinterpret_cast<const float4*>(u) + (size_t)b * TT;
  for (int idx = tid; idx < TT; idx += NTHREADS) {
    y_lds[idx] = yg[idx];
    u_lds[idx] = ug[idx];
  }

  // ---- one-time: resident weights ----
  // Wh column slice: w[kk] = Wh[k0+kk][j]  (coalesced over j)
  float w[64];
  #pragma unroll
  for (int kk = 0; kk < 64; ++kk) w[kk] = Wh[(size_t)(k0 + kk) * G3 + j];

  // input-projection column (used by c==0, j<256: r and z gates)
  float wi[8];
  #pragma unroll
  for (int d = 0; d < 8; ++d) wi[d] = Wi[d * G3 + j];
  const float bij = bi[j];

  // pointwise-thread (tid<128) state: n-gate input proj + biases
  float wn[8];
  float bin = 0.f, bh = 0.f, h = 0.f;
  double hsum = 0.0;
  if (tid < HN) {
    #pragma unroll
    for (int d = 0; d < 8; ++d) wn[d] = Wi[d * G3 + 256 + tid];
    bin = bi[256 + tid];
    bh  = bhn[tid];
    h_lds[tid] = 0.f;
  }
  __syncthreads();

  for (int t = 0; t < TT; ++t) {
    const int te = dir ? (TT - 1 - t) : t;
    const float4 yv = y_lds[te];   // broadcast LDS reads
    const float4 uv = u_lds[te];

    // ---- hp partial: dot(h[k0..k0+63], Wh[:,j]) with 4 accumulators ----
    float a0 = 0.f, a1 = 0.f, a2 = 0.f, a3 = 0.f;
    const float4* h4 = reinterpret_cast<const float4*>(h_lds) + c * 16;
    #pragma unroll
    for (int q = 0; q < 16; ++q) {
      const float4 hv = h4[q];
      a0 = fmaf(hv.x, w[4*q+0], a0);
      a1 = fmaf(hv.y, w[4*q+1], a1);
      a2 = fmaf(hv.z, w[4*q+2], a2);
      a3 = fmaf(hv.w, w[4*q+3], a3);
    }
    float acc = (a0 + a1) + (a2 + a3);

    // fold x@Wi + bi into r/z partials only (n-gate xw must stay outside r*(...))
    float xa = bij;
    xa = fmaf(yv.x, wi[0], xa); xa = fmaf(yv.y, wi[1], xa);
    xa = fmaf(yv.z, wi[2], xa); xa = fmaf(yv.w, wi[3], xa);
    xa = fmaf(uv.x, wi[4], xa); xa = fmaf(uv.y, wi[5], xa);
    xa = fmaf(uv.z, wi[6], xa); xa = fmaf(uv.w, wi[7], xa);
    if (c == 0 && j < 256) acc += xa;

    hp_part[c][j] = acc;
    __syncthreads();

    // ---- gate math on 128 pointwise threads ----
    if (tid < HN) {
      const float pr = hp_part[0][tid]       + hp_part[1][tid];
      const float pz = hp_part[0][tid + 128] + hp_part[1][tid + 128];
      const float pn = hp_part[0][tid + 256] + hp_part[1][tid + 256];
      float xan = bin;
      xan = fmaf(yv.x, wn[0], xan); xan = fmaf(yv.y, wn[1], xan);
      xan = fmaf(yv.z, wn[2], xan); xan = fmaf(yv.w, wn[3], xan);
      xan = fmaf(uv.x, wn[4], xan); xan = fmaf(uv.y, wn[5], xan);
      xan = fmaf(uv.z, wn[6], xan); xan = fmaf(uv.w, wn[7], xan);
      const float r = fast_sigmoid(pr);
      const float z = fast_sigmoid(pz);
      const float n = fast_tanh(xan + r * (pn + bh));
      h = (1.0f - z) * n + z * h;
      hsum += (double)h;
      h_lds[tid] = h;
    }
    __syncthreads();
  }

  if (tid < HN) {
    feat[(size_t)b * 256 + dir * HN + tid] = (float)(hsum * (1.0 / TT));
  }
}

// ---- tiny MLP heads: feat[64,256] -> (m[64,20], s[64,20]) ----
__global__ __launch_bounds__(128) void mlp_kernel(
    const float* __restrict__ feat,
    const float* __restrict__ mW0, const float* __restrict__ mb0,
    const float* __restrict__ mW1, const float* __restrict__ mb1,
    const float* __restrict__ mW2, const float* __restrict__ mb2,
    const float* __restrict__ sW0, const float* __restrict__ sb0,
    const float* __restrict__ sW1, const float* __restrict__ sb1,
    const float* __restrict__ sW2, const float* __restrict__ sb2,
    float* __restrict__ out)
{
  const int b = blockIdx.x;
  const int tid = threadIdx.x;
  __shared__ float f[256];
  __shared__ float h1[128];
  __shared__ float h2[64];

  f[tid]       = feat[b * 256 + tid];
  f[tid + 128] = feat[b * 256 + 128 + tid];
  __syncthreads();

  for (int head = 0; head < 2; ++head) {
    const float* __restrict__ W0 = head ? sW0 : mW0;
    const float* __restrict__ b0 = head ? sb0 : mb0;
    const float* __restrict__ W1 = head ? sW1 : mW1;
    const float* __restrict__ b1 = head ? sb1 : mb1;
    const float* __restrict__ W2 = head ? sW2 : mW2;
    const float* __restrict__ b2 = head ? sb2 : mb2;

    float a = b0[tid];
    for (int k = 0; k < 256; ++k) a = fmaf(f[k], W0[k * 128 + tid], a);
    h1[tid] = fast_tanh(a);
    __syncthreads();

    if (tid < 64) {
      float a1 = b1[tid];
      for (int k = 0; k < 128; ++k) a1 = fmaf(h1[k], W1[k * 64 + tid], a1);
      h2[tid] = fast_tanh(a1);
    }
    __syncthreads();

    if (tid < 20) {
      float a2 = b2[tid];
      for (int k = 0; k < 64; ++k) a2 = fmaf(h2[k], W2[k * 20 + tid], a2);
      out[head * (BATCH * 20) + b * 20 + tid] = a2;
    }
    __syncthreads();
  }
}

extern "C" void kernel_launch(void* const* d_in, const int* in_sizes, int n_in,
                              void* d_out, int out_size, void* d_ws, size_t ws_size,
                              hipStream_t stream) {
  const float* y     = (const float*)d_in[0];
  const float* u     = (const float*)d_in[1];
  const float* Wi_f  = (const float*)d_in[2];
  const float* bi_f  = (const float*)d_in[3];
  const float* Wh_f  = (const float*)d_in[4];
  const float* bhn_f = (const float*)d_in[5];
  const float* Wi_b  = (const float*)d_in[6];
  const float* bi_b  = (const float*)d_in[7];
  const float* Wh_b  = (const float*)d_in[8];
  const float* bhn_b = (const float*)d_in[9];
  const float* mW0 = (const float*)d_in[10]; const float* mb0 = (const float*)d_in[11];
  const float* mW1 = (const float*)d_in[12]; const float* mb1 = (const float*)d_in[13];
  const float* mW2 = (const float*)d_in[14]; const float* mb2 = (const float*)d_in[15];
  const float* sW0 = (const float*)d_in[16]; const float* sb0 = (const float*)d_in[17];
  const float* sW1 = (const float*)d_in[18]; const float* sb1 = (const float*)d_in[19];
  const float* sW2 = (const float*)d_in[20]; const float* sb2 = (const float*)d_in[21];

  float* feat = (float*)d_ws;  // [64, 256]
  float* out  = (float*)d_out; // m[64,20] then s[64,20]

  gru_scan_kernel<<<BATCH * 2, NTHREADS, 0, stream>>>(
      y, u, Wi_f, bi_f, Wh_f, bhn_f, Wi_b, bi_b, Wh_b, bhn_b, feat);
  mlp_kernel<<<BATCH, 128, 0, stream>>>(
      feat, mW0, mb0, mW1, mb1, mW2, mb2, sW0, sb0, sW1, sb1, sW2, sb2, out);
}

// Round 2
// 1506.295 us; speedup vs baseline: 1.4632x; 1.4632x over previous
//
#include <hip/hip_runtime.h>
#include <hip/hip_bf16.h>

#define HN 128        // rnn_size
#define TT 2048       // time steps
#define BATCH 64
#define G3 384        // 3*H
#define NT 512        // 8 k-groups x 64 column-groups
#define HPLD (G3 + 4) // padded row for hp partials

__device__ __forceinline__ float fast_sigmoid(float x) {
  float e = __builtin_amdgcn_exp2f(-x * 1.44269504088896340736f);
  return __builtin_amdgcn_rcpf(1.0f + e);
}
__device__ __forceinline__ float fast_tanh(float x) {
  float e = __builtin_amdgcn_exp2f(x * 2.88539008177792681472f);
  return 1.0f - 2.0f * __builtin_amdgcn_rcpf(e + 1.0f);
}

// One block per (batch, direction) chain: 128 blocks, 1 per CU.
// Thread (kg,cg): kg = tid>>6 in [0,8), cg = tid&63.
//   Holds Wh tile w[16][6]: rows kg*16..+15, cols j = cg + 64*ci (ci 0..5).
//   Per step: reads 16 h floats (4 broadcast b128), 96 FMAs -> 6 partials.
//   Folds input-proj x[kg]*Wi[kg][j] into partials for j<256 (r,z gates only).
// Gate phase: threads 0..127 reduce 8 partials x 3 gates (24 b32, lane-consecutive),
//   compute r/z/n, update h, accumulate mean in double.
__global__ __launch_bounds__(NT, 2) void gru_scan_kernel(
    const float* __restrict__ y, const float* __restrict__ u,
    const float* __restrict__ Wi_f, const float* __restrict__ bi_f,
    const float* __restrict__ Wh_f, const float* __restrict__ bhn_f,
    const float* __restrict__ Wi_b, const float* __restrict__ bi_b,
    const float* __restrict__ Wh_b, const float* __restrict__ bhn_b,
    float* __restrict__ feat)
{
  const int b   = blockIdx.x >> 1;
  const int dir = blockIdx.x & 1;
  const float* __restrict__ Wi  = dir ? Wi_b  : Wi_f;
  const float* __restrict__ bi  = dir ? bi_b  : bi_f;
  const float* __restrict__ Wh  = dir ? Wh_b  : Wh_f;
  const float* __restrict__ bhn = dir ? bhn_b : bhn_f;

  const int tid = threadIdx.x;
  const int kg  = tid >> 6;    // 0..7: k-group AND input dim d
  const int cg  = tid & 63;    // 0..63: column group
  const int k0  = kg * 16;

  __shared__ float4 y_lds[TT];        // 32 KB
  __shared__ float4 u_lds[TT];        // 32 KB
  __shared__ float  h_lds[HN];
  __shared__ float  hp[8][HPLD];      // per-kg partials, padded rows

  // ---- stage y/u rows (coalesced float4) ----
  const float4* yg = reinterpret_cast<const float4*>(y) + (size_t)b * TT;
  const float4* ug = reinterpret_cast<const float4*>(u) + (size_t)b * TT;
  for (int idx = tid; idx < TT; idx += NT) {
    y_lds[idx] = yg[idx];
    u_lds[idx] = ug[idx];
  }

  // ---- resident Wh tile: w[kk][ci] = Wh[k0+kk][cg + 64*ci] (coalesced over cg) ----
  float w[16][6];
  #pragma unroll
  for (int kk = 0; kk < 16; ++kk)
    #pragma unroll
    for (int ci = 0; ci < 6; ++ci)
      w[kk][ci] = Wh[(size_t)(k0 + kk) * G3 + cg + 64 * ci];

  // input-proj weights for this thread's r/z columns (ci<4 -> j<256)
  float wi[4];
  #pragma unroll
  for (int ci = 0; ci < 4; ++ci) wi[ci] = Wi[kg * G3 + cg + 64 * ci];

  // per-step x[kg] source: broadcast b32 from staged rows
  const float* xsrc = (kg < 4) ? (reinterpret_cast<const float*>(y_lds) + kg)
                               : (reinterpret_cast<const float*>(u_lds) + (kg - 4));

  // ---- gate-thread state (tid < 128) ----
  float wn[8];
  float bin = 0.f, bh = 0.f, bir = 0.f, biz = 0.f, h = 0.f;
  double hsum = 0.0;
  if (tid < HN) {
    #pragma unroll
    for (int d = 0; d < 8; ++d) wn[d] = Wi[d * G3 + 256 + tid];
    bin = bi[256 + tid];
    bir = bi[tid];
    biz = bi[128 + tid];
    bh  = bhn[tid];
    h_lds[tid] = 0.f;
  }
  __syncthreads();

  for (int t = 0; t < TT; ++t) {
    const int te = dir ? (TT - 1 - t) : t;
    const float xk = xsrc[te * 4];

    // ---- 16x6 partial GEMV: 4 broadcast b128 h-reads, 96 FMAs ----
    float a[6];
    #pragma unroll
    for (int ci = 0; ci < 6; ++ci) a[ci] = (ci < 4) ? xk * wi[ci] : 0.f;

    const float4* h4 = reinterpret_cast<const float4*>(h_lds) + kg * 4;
    #pragma unroll
    for (int q = 0; q < 4; ++q) {
      const float4 hv = h4[q];
      #pragma unroll
      for (int ci = 0; ci < 6; ++ci) {
        a[ci] = fmaf(hv.x, w[4*q+0][ci], a[ci]);
        a[ci] = fmaf(hv.y, w[4*q+1][ci], a[ci]);
        a[ci] = fmaf(hv.z, w[4*q+2][ci], a[ci]);
        a[ci] = fmaf(hv.w, w[4*q+3][ci], a[ci]);
      }
    }
    #pragma unroll
    for (int ci = 0; ci < 6; ++ci) hp[kg][cg + 64 * ci] = a[ci];
    __syncthreads();

    // ---- gate math on threads 0..127 ----
    if (tid < HN) {
      float pr = bir, pz = biz, pn = 0.f;
      #pragma unroll
      for (int g = 0; g < 8; ++g) {
        pr += hp[g][tid];
        pz += hp[g][tid + 128];
        pn += hp[g][tid + 256];
      }
      const float4 yv = y_lds[te];
      const float4 uv = u_lds[te];
      float xan = bin;
      xan = fmaf(yv.x, wn[0], xan); xan = fmaf(yv.y, wn[1], xan);
      xan = fmaf(yv.z, wn[2], xan); xan = fmaf(yv.w, wn[3], xan);
      xan = fmaf(uv.x, wn[4], xan); xan = fmaf(uv.y, wn[5], xan);
      xan = fmaf(uv.z, wn[6], xan); xan = fmaf(uv.w, wn[7], xan);
      const float r = fast_sigmoid(pr);
      const float z = fast_sigmoid(pz);
      const float n = fast_tanh(xan + r * (pn + bh));
      h = (1.0f - z) * n + z * h;
      hsum += (double)h;
      h_lds[tid] = h;
    }
    __syncthreads();
  }

  if (tid < HN) {
    feat[(size_t)b * 256 + dir * HN + tid] = (float)(hsum * (1.0 / TT));
  }
}

// ---- tiny MLP heads: feat[64,256] -> (m[64,20], s[64,20]) ----
__global__ __launch_bounds__(128) void mlp_kernel(
    const float* __restrict__ feat,
    const float* __restrict__ mW0, const float* __restrict__ mb0,
    const float* __restrict__ mW1, const float* __restrict__ mb1,
    const float* __restrict__ mW2, const float* __restrict__ mb2,
    const float* __restrict__ sW0, const float* __restrict__ sb0,
    const float* __restrict__ sW1, const float* __restrict__ sb1,
    const float* __restrict__ sW2, const float* __restrict__ sb2,
    float* __restrict__ out)
{
  const int b = blockIdx.x;
  const int tid = threadIdx.x;
  __shared__ float f[256];
  __shared__ float h1[128];
  __shared__ float h2[64];

  f[tid]       = feat[b * 256 + tid];
  f[tid + 128] = feat[b * 256 + 128 + tid];
  __syncthreads();

  for (int head = 0; head < 2; ++head) {
    const float* __restrict__ W0 = head ? sW0 : mW0;
    const float* __restrict__ b0 = head ? sb0 : mb0;
    const float* __restrict__ W1 = head ? sW1 : mW1;
    const float* __restrict__ b1 = head ? sb1 : mb1;
    const float* __restrict__ W2 = head ? sW2 : mW2;
    const float* __restrict__ b2 = head ? sb2 : mb2;

    float a = b0[tid];
    for (int k = 0; k < 256; ++k) a = fmaf(f[k], W0[k * 128 + tid], a);
    h1[tid] = fast_tanh(a);
    __syncthreads();

    if (tid < 64) {
      float a1 = b1[tid];
      for (int k = 0; k < 128; ++k) a1 = fmaf(h1[k], W1[k * 64 + tid], a1);
      h2[tid] = fast_tanh(a1);
    }
    __syncthreads();

    if (tid < 20) {
      float a2 = b2[tid];
      for (int k = 0; k < 64; ++k) a2 = fmaf(h2[k], W2[k * 20 + tid], a2);
      out[head * (BATCH * 20) + b * 20 + tid] = a2;
    }
    __syncthreads();
  }
}

extern "C" void kernel_launch(void* const* d_in, const int* in_sizes, int n_in,
                              void* d_out, int out_size, void* d_ws, size_t ws_size,
                              hipStream_t stream) {
  const float* y     = (const float*)d_in[0];
  const float* u     = (const float*)d_in[1];
  const float* Wi_f  = (const float*)d_in[2];
  const float* bi_f  = (const float*)d_in[3];
  const float* Wh_f  = (const float*)d_in[4];
  const float* bhn_f = (const float*)d_in[5];
  const float* Wi_b  = (const float*)d_in[6];
  const float* bi_b  = (const float*)d_in[7];
  const float* Wh_b  = (const float*)d_in[8];
  const float* bhn_b = (const float*)d_in[9];
  const float* mW0 = (const float*)d_in[10]; const float* mb0 = (const float*)d_in[11];
  const float* mW1 = (const float*)d_in[12]; const float* mb1 = (const float*)d_in[13];
  const float* mW2 = (const float*)d_in[14]; const float* mb2 = (const float*)d_in[15];
  const float* sW0 = (const float*)d_in[16]; const float* sb0 = (const float*)d_in[17];
  const float* sW1 = (const float*)d_in[18]; const float* sb1 = (const float*)d_in[19];
  const float* sW2 = (const float*)d_in[20]; const float* sb2 = (const float*)d_in[21];

  float* feat = (float*)d_ws;  // [64, 256]
  float* out  = (float*)d_out; // m[64,20] then s[64,20]

  gru_scan_kernel<<<BATCH * 2, NT, 0, stream>>>(
      y, u, Wi_f, bi_f, Wh_f, bhn_f, Wi_b, bi_b, Wh_b, bhn_b, feat);
  mlp_kernel<<<BATCH, 128, 0, stream>>>(
      feat, mW0, mb0, mW1, mb1, mW2, mb2, sW0, sb0, sW1, sb1, sW2, sb2, out);
}

// Round 3
// 1204.180 us; speedup vs baseline: 1.8303x; 1.2509x over previous
//
#include <hip/hip_runtime.h>
#include <hip/hip_bf16.h>

#define HN 128        // rnn_size
#define TT 2048       // time steps
#define BATCH 64
#define G3 384        // 3*H
#define NT 512        // 128 j-rows x 4 k-slices
#define REPLD 136     // replica row pitch (floats): bank shift of 8 per replica

__device__ __forceinline__ float fast_sigmoid(float x) {
  float e = __builtin_amdgcn_exp2f(-x * 1.44269504088896340736f);
  return __builtin_amdgcn_rcpf(1.0f + e);
}
__device__ __forceinline__ float fast_tanh(float x) {
  float e = __builtin_amdgcn_exp2f(x * 2.88539008177792681472f);
  return 1.0f - 2.0f * __builtin_amdgcn_rcpf(e + 1.0f);
}
// quad-perm butterfly: after xor1+xor2 all 4 lanes of a quad hold the full sum
__device__ __forceinline__ float dpp_xor1(float x) {
  return __int_as_float(__builtin_amdgcn_mov_dpp(__float_as_int(x), 0xB1, 0xF, 0xF, true));
}
__device__ __forceinline__ float dpp_xor2(float x) {
  return __int_as_float(__builtin_amdgcn_mov_dpp(__float_as_int(x), 0x4E, 0xF, 0xF, true));
}
__device__ __forceinline__ float quad_sum(float v) {
  v += dpp_xor1(v);
  v += dpp_xor2(v);
  return v;
}

// One block per (batch, direction): 128 blocks. Thread (j,p): j=tid>>2 output
// row, p=tid&3 k-slice of 32. No gate phase: DPP butterfly reduce + redundant
// gate math in all 4 quad lanes; h double-buffered + 4-replicated in LDS so
// one barrier/step and conflict-free b128 reads.
__global__ __launch_bounds__(NT, 2) void gru_scan_kernel(
    const float* __restrict__ y, const float* __restrict__ u,
    const float* __restrict__ Wi_f, const float* __restrict__ bi_f,
    const float* __restrict__ Wh_f, const float* __restrict__ bhn_f,
    const float* __restrict__ Wi_b, const float* __restrict__ bi_b,
    const float* __restrict__ Wh_b, const float* __restrict__ bhn_b,
    float* __restrict__ feat)
{
  const int b   = blockIdx.x >> 1;
  const int dir = blockIdx.x & 1;
  const float* __restrict__ Wi  = dir ? Wi_b  : Wi_f;
  const float* __restrict__ bi  = dir ? bi_b  : bi_f;
  const float* __restrict__ Wh  = dir ? Wh_b  : Wh_f;
  const float* __restrict__ bhn = dir ? bhn_b : bhn_f;

  const int tid = threadIdx.x;
  const int j   = tid >> 2;    // 0..127 output row
  const int p   = tid & 3;     // 0..3  k-slice
  const int k0  = p * 32;

  __shared__ float4 y_lds[TT];            // 32 KB
  __shared__ float4 u_lds[TT];            // 32 KB
  __shared__ float  h_rep[2][4][REPLD];   // double-buffered, 4 replicas

  // ---- stage y/u (coalesced float4) ----
  const float4* yg = reinterpret_cast<const float4*>(y) + (size_t)b * TT;
  const float4* ug = reinterpret_cast<const float4*>(u) + (size_t)b * TT;
  for (int idx = tid; idx < TT; idx += NT) {
    y_lds[idx] = yg[idx];
    u_lds[idx] = ug[idx];
  }

  // ---- resident Wh tile: w[kk][g] = Wh[k0+kk][g*128 + j] ----
  float w[32][3];
  #pragma unroll
  for (int kk = 0; kk < 32; ++kk) {
    const size_t row = (size_t)(k0 + kk) * G3;
    w[kk][0] = Wh[row + j];
    w[kk][1] = Wh[row + 128 + j];
    w[kk][2] = Wh[row + 256 + j];
  }

  // input-proj weights: lane p owns dims {2p, 2p+1}
  const int d0 = 2 * p, d1 = 2 * p + 1;
  const float wir0 = Wi[d0 * G3 + j],       wir1 = Wi[d1 * G3 + j];
  const float wiz0 = Wi[d0 * G3 + 128 + j], wiz1 = Wi[d1 * G3 + 128 + j];
  const float wn0  = Wi[d0 * G3 + 256 + j], wn1  = Wi[d1 * G3 + 256 + j];
  const float bir = bi[j], biz = bi[128 + j], bin = bi[256 + j], bh = bhn[j];

  // per-step x[d0],x[d1] broadcast source (d<4 -> y, else u)
  const float* yf = reinterpret_cast<const float*>(y_lds);
  const float* uf = reinterpret_cast<const float*>(u_lds);
  const float* xsrc = (p < 2) ? (yf + d0) : (uf + d0 - 4);

  float h = 0.f;
  double hsum = 0.0;
  h_rep[0][p][j] = 0.f;
  __syncthreads();

  const int te0 = dir ? (TT - 1) : 0;
  const int dte = dir ? -1 : 1;
  int cur = 0;
  int te = te0;

  for (int t = 0; t < TT; ++t, te += dte) {
    const float xd0 = xsrc[te * 4];
    const float xd1 = xsrc[te * 4 + 1];

    // partials: r/z include distributed x-proj; n-gate x-proj (ax) separate
    float ar = xd0 * wir0; ar = fmaf(xd1, wir1, ar);
    float az = xd0 * wiz0; az = fmaf(xd1, wiz1, az);
    float ax = xd0 * wn0;  ax = fmaf(xd1, wn1, ax);
    float an = 0.f;

    // 32x3 FMAs from replica p (conflict-free b128: bank start 4q+8p)
    const float4* h4 = reinterpret_cast<const float4*>(&h_rep[cur][p][k0]);
    #pragma unroll
    for (int q = 0; q < 8; ++q) {
      const float4 hv = h4[q];
      ar = fmaf(hv.x, w[4*q+0][0], ar); az = fmaf(hv.x, w[4*q+0][1], az); an = fmaf(hv.x, w[4*q+0][2], an);
      ar = fmaf(hv.y, w[4*q+1][0], ar); az = fmaf(hv.y, w[4*q+1][1], az); an = fmaf(hv.y, w[4*q+1][2], an);
      ar = fmaf(hv.z, w[4*q+2][0], ar); az = fmaf(hv.z, w[4*q+2][1], az); an = fmaf(hv.z, w[4*q+2][2], an);
      ar = fmaf(hv.w, w[4*q+3][0], ar); az = fmaf(hv.w, w[4*q+3][1], az); an = fmaf(hv.w, w[4*q+3][2], an);
    }

    // DPP butterfly: all 4 quad lanes get full sums (bit-identical)
    ar = quad_sum(ar);
    az = quad_sum(az);
    an = quad_sum(an);
    ax = quad_sum(ax);

    const float r = fast_sigmoid(ar + bir);
    const float z = fast_sigmoid(az + biz);
    const float n = fast_tanh((ax + bin) + r * (an + bh));
    h = (1.0f - z) * n + z * h;
    hsum += (double)h;

    h_rep[cur ^ 1][p][j] = h;   // each lane writes its replica (2-way = free)
    __syncthreads();
    cur ^= 1;
  }

  if (p == 0) {
    feat[(size_t)b * 256 + dir * HN + j] = (float)(hsum * (1.0 / TT));
  }
}

// ---- tiny MLP heads: feat[64,256] -> (m[64,20], s[64,20]) ----
__global__ __launch_bounds__(128) void mlp_kernel(
    const float* __restrict__ feat,
    const float* __restrict__ mW0, const float* __restrict__ mb0,
    const float* __restrict__ mW1, const float* __restrict__ mb1,
    const float* __restrict__ mW2, const float* __restrict__ mb2,
    const float* __restrict__ sW0, const float* __restrict__ sb0,
    const float* __restrict__ sW1, const float* __restrict__ sb1,
    const float* __restrict__ sW2, const float* __restrict__ sb2,
    float* __restrict__ out)
{
  const int b = blockIdx.x;
  const int tid = threadIdx.x;
  __shared__ float f[256];
  __shared__ float h1[128];
  __shared__ float h2[64];

  f[tid]       = feat[b * 256 + tid];
  f[tid + 128] = feat[b * 256 + 128 + tid];
  __syncthreads();

  for (int head = 0; head < 2; ++head) {
    const float* __restrict__ W0 = head ? sW0 : mW0;
    const float* __restrict__ b0 = head ? sb0 : mb0;
    const float* __restrict__ W1 = head ? sW1 : mW1;
    const float* __restrict__ b1 = head ? sb1 : mb1;
    const float* __restrict__ W2 = head ? sW2 : mW2;
    const float* __restrict__ b2 = head ? sb2 : mb2;

    float a = b0[tid];
    for (int k = 0; k < 256; ++k) a = fmaf(f[k], W0[k * 128 + tid], a);
    h1[tid] = fast_tanh(a);
    __syncthreads();

    if (tid < 64) {
      float a1 = b1[tid];
      for (int k = 0; k < 128; ++k) a1 = fmaf(h1[k], W1[k * 64 + tid], a1);
      h2[tid] = fast_tanh(a1);
    }
    __syncthreads();

    if (tid < 20) {
      float a2 = b2[tid];
      for (int k = 0; k < 64; ++k) a2 = fmaf(h2[k], W2[k * 20 + tid], a2);
      out[head * (BATCH * 20) + b * 20 + tid] = a2;
    }
    __syncthreads();
  }
}

extern "C" void kernel_launch(void* const* d_in, const int* in_sizes, int n_in,
                              void* d_out, int out_size, void* d_ws, size_t ws_size,
                              hipStream_t stream) {
  const float* y     = (const float*)d_in[0];
  const float* u     = (const float*)d_in[1];
  const float* Wi_f  = (const float*)d_in[2];
  const float* bi_f  = (const float*)d_in[3];
  const float* Wh_f  = (const float*)d_in[4];
  const float* bhn_f = (const float*)d_in[5];
  const float* Wi_b  = (const float*)d_in[6];
  const float* bi_b  = (const float*)d_in[7];
  const float* Wh_b  = (const float*)d_in[8];
  const float* bhn_b = (const float*)d_in[9];
  const float* mW0 = (const float*)d_in[10]; const float* mb0 = (const float*)d_in[11];
  const float* mW1 = (const float*)d_in[12]; const float* mb1 = (const float*)d_in[13];
  const float* mW2 = (const float*)d_in[14]; const float* mb2 = (const float*)d_in[15];
  const float* sW0 = (const float*)d_in[16]; const float* sb0 = (const float*)d_in[17];
  const float* sW1 = (const float*)d_in[18]; const float* sb1 = (const float*)d_in[19];
  const float* sW2 = (const float*)d_in[20]; const float* sb2 = (const float*)d_in[21];

  float* feat = (float*)d_ws;  // [64, 256]
  float* out  = (float*)d_out; // m[64,20] then s[64,20]

  gru_scan_kernel<<<BATCH * 2, NT, 0, stream>>>(
      y, u, Wi_f, bi_f, Wh_f, bhn_f, Wi_b, bi_b, Wh_b, bhn_b, feat);
  mlp_kernel<<<BATCH, 128, 0, stream>>>(
      feat, mW0, mb0, mW1, mb1, mW2, mb2, sW0, sb0, sW1, sb1, sW2, sb2, out);
}